// Round 9
// baseline (2908.093 us; speedup 1.0000x reference)
//
#include <hip/hip_runtime.h>
#include <hip/hip_bf16.h>
#include <cstddef>
#include <cstdint>

#define B_ 4
#define N_ 2048
#define DIM_ 768
#define HEADS_ 12
#define DH_ 64
#define DEPTH_ 4
#define W_ 35
#define P_ 384
#define V4_ 192
#define FF_ 3072
#define NW_ 59                 // windows per batch (pad 17)
#define NPB_ (NW_*W_)          // 2065 padded tokens per batch
#define NTOK_ (B_*N_)          // 8192
#define NWB_ (B_*NW_)          // 236 windows total
#define NTP_ (NWB_*W_)         // 8260 padded tokens total
#define NTPA_ 8448             // NTP rounded up for 256-row A tiles
#define NEG_ 3.402823466e+38f
#define QLD_ 65                // padded q/k LDS row stride (bank-conflict fix)

typedef __bf16 bf16x8 __attribute__((ext_vector_type(8)));
typedef float  f32x4  __attribute__((ext_vector_type(4)));

// async global->LDS, 16B per lane (global src per-lane, LDS dst = base+lane*16)
#define GLOAD16(g, l) __builtin_amdgcn_global_load_lds( \
    (const __attribute__((address_space(1))) uint32_t*)(g), \
    (__attribute__((address_space(3))) uint32_t*)(l), 16, 0, 0)

// ---------------------------------------------------------------- setup

__global__ __launch_bounds__(192) void posbias1_k(
    const float* __restrict__ W1, const float* __restrict__ b1,
    const float* __restrict__ W2, const float* __restrict__ b2,
    const float* __restrict__ W3, const float* __restrict__ b3,
    float* __restrict__ outk)
{
    __shared__ float h1[192];
    __shared__ float h2[192];
    int i = blockIdx.x;
    int tid = threadIdx.x;
    float pos = (float)(i - 34);
    h1[tid] = fmaxf(pos*W1[tid] + b1[tid], 0.f);
    __syncthreads();
    float s = b2[tid];
    for (int k=0;k<192;k++) s += h1[k]*W2[k*192+tid];
    h2[tid] = fmaxf(s, 0.f);
    __syncthreads();
    if (tid < 12){
        float o = b3[tid];
        for (int k=0;k<192;k++) o += h2[k]*W3[k*12+tid];
        outk[i*12+tid] = o;
    }
}

__global__ void posbias2_k(const float* __restrict__ outk, float* __restrict__ bias)
{
    int e = threadIdx.x + blockIdx.x*blockDim.x;
    if (e >= HEADS_*W_*W_) return;
    int h=e/(W_*W_); int rem=e%(W_*W_); int i=rem/W_; int j=rem%W_;
    bias[e] = outk[(i-j+W_-1)*12 + h];
}

__global__ void sinu_k(float* __restrict__ sinu)
{
    int i = blockIdx.x;      // 0..34
    int k = threadIdx.x;     // 0..191
    float inv = powf(10000.f, -(float)k/192.f);
    float s = (float)i * inv;
    sinu[i*P_ + k]       = sinf(s);
    sinu[i*P_ + 192 + k] = cosf(s);
}

__global__ void len_k(const unsigned char* __restrict__ mask, float* __restrict__ len)
{
    int bw = threadIdx.x + blockIdx.x*blockDim.x;
    if (bw >= NWB_) return;
    int b = bw / NW_, w = bw % NW_;
    int cnt = 0;
    for (int t=0;t<W_;t++){
        int g = w*W_ + t;
        if (g < N_ && mask[b*N_+g]==0) cnt++;
    }
    len[bw] = fmaxf((float)cnt, 1.f);
}

// weight pack: fp32 [K][N] -> bf16 [K/8][Nld][8]; dst col = ncol0+n, src col n
// (or qkv-permuted). n in [N,Ncov) zero-fills. grid.x covers Ncov.
__global__ __launch_bounds__(256) void pack_k(
    const float* __restrict__ W, __bf16* __restrict__ Bp,
    int N, int Ncov, int Nld, size_t lsW, size_t lsB, int qkvperm, int ncol0)
{
    int n = blockIdx.x*256 + threadIdx.x;
    int k8 = blockIdx.y, l = blockIdx.z;
    if (n >= Ncov) return;
    bf16x8 v;
    if (n < N){
        int sn = n;
        if (qkvperm){ int s = n/768, hd = n - s*768; sn = hd*3 + s; }
        const float* w = W + lsW*l + (size_t)k8*8*N + sn;
        #pragma unroll
        for (int e=0;e<8;e++) v[e] = (__bf16)w[(size_t)e*N];
    } else {
        #pragma unroll
        for (int e=0;e<8;e++) v[e] = (__bf16)0.f;
    }
    *(bf16x8*)(Bp + lsB*l + ((size_t)k8*Nld + ncol0 + n)*8) = v;
}

// ---------------------------------------------------------------- layernorm
// o2p != null (padded=0 only): normalize (x + o2p_broadcast) per reference.
__global__ __launch_bounds__(256) void ln_k(
    const float* __restrict__ x, const float* __restrict__ g,
    const float* __restrict__ b, __bf16* __restrict__ out,
    const float* __restrict__ o2p, int padded)
{
    int r = blockIdx.x;
    int tid = threadIdx.x;
    int lane = tid & 63, wave = tid >> 6;
    int row = r; bool real = true;
    if (padded){
        int bb = r / NPB_, n = r % NPB_;
        if (n >= N_) real = false;
        row = bb*N_ + n;
    }
    float v0=0,v1=0,v2=0;
    if (real){
        const float* xr = x + (size_t)row*DIM_;
        v0 = xr[tid]; v1 = xr[tid+256]; v2 = xr[tid+512];
        if (o2p){
            int bb = row / N_, nn = row % N_;
            const float* op = o2p + (size_t)(bb*NW_ + nn/W_)*DIM_;
            v0 += op[tid]; v1 += op[tid+256]; v2 += op[tid+512];
        }
    }
    float s1 = v0+v1+v2;
    float s2 = v0*v0+v1*v1+v2*v2;
    #pragma unroll
    for (int off=32; off; off>>=1){
        s1 += __shfl_xor(s1, off);
        s2 += __shfl_xor(s2, off);
    }
    __shared__ float a1[4], a2[4];
    if (lane==0){ a1[wave]=s1; a2[wave]=s2; }
    __syncthreads();
    s1 = a1[0]+a1[1]+a1[2]+a1[3];
    s2 = a2[0]+a2[1]+a2[2]+a2[3];
    float m   = s1 * (1.f/768.f);
    float var = s2 * (1.f/768.f) - m*m;
    float inv = rsqrtf(var + 1e-5f);
    __bf16* o = out + (size_t)r*DIM_;
    if (!real){ o[tid]=(__bf16)0.f; o[tid+256]=(__bf16)0.f; o[tid+512]=(__bf16)0.f; return; }
    o[tid]     = (__bf16)((v0-m)*inv*g[tid]     + b[tid]);
    o[tid+256] = (__bf16)((v1-m)*inv*g[tid+256] + b[tid+256]);
    o[tid+512] = (__bf16)((v2-m)*inv*g[tid+512] + b[tid+512]);
}

// ---------------------------------------------------------------- MFMA GEMM
// Tri-buffered LDS, one raw s_barrier per K-step, counted vmcnt(NL)
// (2-deep prefetch stays in flight across barriers; drain only at last step).
// 256 threads, 4 waves 2Mx2N. BM in {64,128,256} -> {8,16,32} MFMA/wave/barrier.
// EPI 1: Cb = acc (bf16)
// EPI 3: FFO: Cf += acc + bias[c] + extra[bw(row)*DIM+c]   (o2p fold, M=8192)
// EPI 4: GLU (DUAL): Cb = (acc+bias[c]) * silu(acc2+bias[c+FF])
// EPI 8: merged: c<384 -> Cf(k2)=acc+sinu*scale ; c<576 -> Cf2(v2)=acc ;
//        else Cx[tok(row)*DIM + c-576] += acc (pad rows skipped)
template<int EPI, bool DUAL, int BM>
__global__ __launch_bounds__(256) void mgemm_k(
    const __bf16* __restrict__ A, const __bf16* __restrict__ Bp,
    float* __restrict__ Cf, __bf16* __restrict__ Cb, float* __restrict__ Cf2,
    float* __restrict__ Cx,
    const float* __restrict__ bias, const float* __restrict__ extra,
    const float* __restrict__ scale_ptr,
    int M, int K, int Nc, int Nld, int Cld)
{
    constexpr int BN = DUAL ? 64 : 128;     // B cols per buffer
    constexpr int RS = BM / 2;              // rows per wave
    constexpr int MF = RS / 16;             // M frags per wave
    constexpr int NF = (BN/2) / 16;         // N frags per wave
    constexpr int AS = BM * 32;             // A elems per buffer
    constexpr int BS = BN * 32;             // B elems per buffer
    constexpr int ALD = BM / 64;            // A gloads per thread
    constexpr int NL  = ALD + 2;            // gloads per thread per tile
    __shared__ alignas(16) __bf16 As[3*AS];
    __shared__ alignas(16) __bf16 Bs[3*BS];
    __shared__ alignas(16) __bf16 Gs[DUAL ? 3*BS : 16];
    const int tid = threadIdx.x;
    const int lane = tid & 63, wave = tid >> 6;
    const int wr = wave >> 1, wc = wave & 1;
    const int m0 = blockIdx.y*BM;
    const int n0 = blockIdx.x*BN;
    const int lk = lane >> 4, lr = lane & 15;
    f32x4 acc[MF][NF] = {};
    f32x4 acc2[DUAL?MF:1][NF] = {};

    // per-thread staging pointers; advance by constants per staged tile
    const __bf16* aP[ALD];
    int aO[ALD];
    #pragma unroll
    for (int q=0;q<ALD;q++){
        int i = tid + q*256;
        int r = i & (BM-1), k8 = i / BM;
        aP[q] = A + (size_t)(m0+r)*K + k8*8;
        aO[q] = i*8;
    }
    const __bf16* bP[2];
    int bO[2];
    if constexpr (!DUAL){
        #pragma unroll
        for (int q=0;q<2;q++){
            int i = tid + q*256;
            int n = i & 127, k8 = i >> 7;
            bP[q] = Bp + ((size_t)k8*Nld + n0 + n)*8;
            bO[q] = i*8;
        }
    } else {
        int n = tid & 63, k8 = tid >> 6;
        bP[0] = Bp + ((size_t)k8*Nld + n0 + n)*8;
        bP[1] = bP[0] + (size_t)FF_*8;
        bO[0] = tid*8;
        bO[1] = tid*8;
    }
    const size_t bStep = (size_t)Nld*32;

    auto stage = [&](int wb){
        #pragma unroll
        for (int q=0;q<ALD;q++)
            GLOAD16(aP[q], As + wb*AS + aO[q]);
        if constexpr (!DUAL){
            GLOAD16(bP[0], Bs + wb*BS + bO[0]);
            GLOAD16(bP[1], Bs + wb*BS + bO[1]);
        } else {
            GLOAD16(bP[0], Bs + wb*BS + bO[0]);
            GLOAD16(bP[1], Gs + wb*BS + bO[1]);
        }
        #pragma unroll
        for (int q=0;q<ALD;q++) aP[q] += 32;
        bP[0] += bStep; bP[1] += bStep;
    };

    const int nk = K >> 5;          // nk >= 24 for all call sites
    stage(0);
    stage(1);
    int rb = 0;
    for (int t = 0; t < nk; ++t){
        if (t == nk-1)              asm volatile("s_waitcnt vmcnt(0)" ::: "memory");
        else if constexpr (NL == 3) asm volatile("s_waitcnt vmcnt(3)" ::: "memory");
        else if constexpr (NL == 4) asm volatile("s_waitcnt vmcnt(4)" ::: "memory");
        else                        asm volatile("s_waitcnt vmcnt(6)" ::: "memory");
        __builtin_amdgcn_s_barrier();
        __builtin_amdgcn_sched_barrier(0);
        if (t + 2 < nk){
            int wb = rb + 2; if (wb >= 3) wb -= 3;
            stage(wb);
        }
        const __bf16* as = As + rb*AS + (size_t)(lk*BM + wr*RS + lr)*8;
        const __bf16* bs = Bs + rb*BS + (size_t)(lk*BN + wc*(BN/2) + lr)*8;
        bf16x8 af[MF], bfr[NF];
        #pragma unroll
        for (int m=0;m<MF;m++) af[m] = *(const bf16x8*)(as + m*128);
        #pragma unroll
        for (int n=0;n<NF;n++) bfr[n] = *(const bf16x8*)(bs + n*128);
        __builtin_amdgcn_s_setprio(1);
        #pragma unroll
        for (int m=0;m<MF;m++)
            #pragma unroll
            for (int n=0;n<NF;n++)
                acc[m][n] = __builtin_amdgcn_mfma_f32_16x16x32_bf16(af[m], bfr[n], acc[m][n], 0,0,0);
        if constexpr (DUAL){
            const __bf16* gs = Gs + rb*BS + (size_t)(lk*BN + wc*(BN/2) + lr)*8;
            bf16x8 gfr[NF];
            #pragma unroll
            for (int n=0;n<NF;n++) gfr[n] = *(const bf16x8*)(gs + n*128);
            #pragma unroll
            for (int m=0;m<MF;m++)
                #pragma unroll
                for (int n=0;n<NF;n++)
                    acc2[m][n] = __builtin_amdgcn_mfma_f32_16x16x32_bf16(af[m], gfr[n], acc2[m][n], 0,0,0);
        }
        __builtin_amdgcn_s_setprio(0);
        rb++; if (rb >= 3) rb = 0;
    }

    const int lq = lane >> 4;
    #pragma unroll
    for (int m=0;m<MF;m++){
        #pragma unroll
        for (int r=0;r<4;r++){
            int row = m0 + wr*RS + m*16 + lq*4 + r;
            if (row >= M) continue;
            #pragma unroll
            for (int n=0;n<NF;n++){
                int col = n0 + wc*(BN/2) + n*16 + lr;
                if (col >= Nc) continue;
                float v = acc[m][n][r];
                if (EPI==1){
                    Cb[(size_t)row*Cld + col] = (__bf16)v;
                } else if (EPI==3){
                    int bb = row / N_, nn = row % N_;
                    int bw = bb*NW_ + nn/W_;
                    Cf[(size_t)row*Cld + col] += v + bias[col]
                        + extra[(size_t)bw*DIM_ + col];
                } else if (EPI==4){
                    float a_ = v + bias[col];
                    float g_ = acc2[m][n][r] + bias[col + FF_];
                    Cb[(size_t)row*Cld + col] = (__bf16)(a_ * (g_ / (1.f + expf(-g_))));
                } else if (EPI==8){
                    if (col < P_){
                        int tt = (row % NPB_) % W_;
                        Cf[(size_t)row*P_ + col] = v + extra[tt*P_ + col]*scale_ptr[0];
                    } else if (col < 576){
                        Cf2[(size_t)row*V4_ + (col - P_)] = v;
                    } else {
                        int bb = row / NPB_, nn = row % NPB_;
                        if (nn < N_)
                            Cx[(size_t)(bb*N_ + nn)*DIM_ + (col - 576)] += v;
                    }
                }
            }
        }
    }
}

// ---------------------------------------------------------------- fp32 GEMM (o2p)
// A is the SHIFTED o2: row bw -> (w==0) ? bos : o2[bw-1]  (o2shift folded in)
__global__ __launch_bounds__(256) void gemm0_k(
    const float* __restrict__ o2, const float* __restrict__ bos,
    const float* __restrict__ Bw, float* __restrict__ C,
    int M, int K, int Nc, int ldb)
{
    __shared__ float As[16][65];
    __shared__ float Bs[16][65];
    const int m0 = blockIdx.y*64, n0 = blockIdx.x*64;
    const int tid = threadIdx.x;
    const int ty = tid>>4, tx = tid&15;
    float acc[4][4] = {};
    for (int k0=0; k0<K; k0+=16){
        #pragma unroll
        for (int i=0;i<4;i++){
            int e = tid + i*256;
            int m = e>>4, kk = e&15;
            int mg = m0+m;
            float v = 0.f;
            if (mg < M){
                int w = mg % NW_;
                v = (w==0) ? bos[k0+kk] : o2[(size_t)(mg-1)*V4_ + k0+kk];
            }
            As[kk][m] = v;
        }
        #pragma unroll
        for (int i=0;i<4;i++){
            int e = tid + i*256;
            int kk = e>>6, n = e&63;
            Bs[kk][n] = Bw[(size_t)(k0+kk)*ldb + n0+n];
        }
        __syncthreads();
        #pragma unroll
        for (int kk=0;kk<16;kk++){
            float a[4], bv[4];
            #pragma unroll
            for (int i=0;i<4;i++) a[i] = As[kk][ty*4+i];
            #pragma unroll
            for (int j=0;j<4;j++) bv[j] = Bs[kk][tx*4+j];
            #pragma unroll
            for (int i=0;i<4;i++)
                #pragma unroll
                for (int j=0;j<4;j++) acc[i][j] += a[i]*bv[j];
        }
        __syncthreads();
    }
    #pragma unroll
    for (int i=0;i<4;i++){
        int mg = m0 + ty*4 + i;
        if (mg >= M) continue;
        #pragma unroll
        for (int j=0;j<4;j++){
            int c = n0 + tx*4 + j;
            if (c >= Nc) continue;
            C[(size_t)mg*Nc + c] = acc[i][j];
        }
    }
}

// ---------------------------------------------------------------- windowed attention (+fused osum)
// qkv layout (permuted pack): row-major [token][ s*768 + h*64 + d ]
// q/k LDS rows padded to QLD_=65 floats: kills the 35-way bank conflict in
// the QK^T and l2norm loops (stride 64 = all lanes on bank d%32).
__global__ __launch_bounds__(256) void attn_k(
    const __bf16* __restrict__ qkv, const unsigned char* __restrict__ mask,
    const float* __restrict__ bias, const float* __restrict__ temp_p,
    __bf16* __restrict__ obuf, float* __restrict__ osum)
{
    int bid = blockIdx.x;
    int w = bid % NW_;
    int h = (bid / NW_) % HEADS_;
    int b = bid / (NW_*HEADS_);
    int tid = threadIdx.x;
    __shared__ float qs[W_*QLD_], ks[W_*QLD_], vs[W_*DH_];
    __shared__ float sc[W_*W_];
    __shared__ float osacc[4][64];
    __shared__ int vf[W_];
    int bw = b*NW_ + w;
    int rbase = bw*W_;
    for (int e=tid; e<W_*DH_; e+=256){
        int t=e>>6, d=e&63;
        size_t idx = (size_t)(rbase+t)*(3*DIM_) + h*DH_ + d;
        qs[t*QLD_+d]=(float)qkv[idx];
        ks[t*QLD_+d]=(float)qkv[idx+768];
        vs[e]=(float)qkv[idx+1536];
    }
    if (tid < W_){
        int g = w*W_ + tid;
        vf[tid] = (g < N_) && (mask[b*N_+g]==0);
    }
    __syncthreads();
    for (int e=tid; e<2*W_; e+=256){
        float* src = (e<W_)? qs : ks;
        int t = (e<W_)? e : e-W_;
        float s=0;
        for (int d=0;d<DH_;d++){ float v=src[t*QLD_+d]; s+=v*v; }
        float inv = 1.f / fmaxf(sqrtf(s), 1e-12f);
        for (int d=0;d<DH_;d++) src[t*QLD_+d] *= inv;
    }
    __syncthreads();
    float temp = temp_p[0];
    for (int e=tid; e<W_*W_; e+=256){
        int i=e/W_, j=e%W_;
        float s;
        if (!vf[i] || !vf[j] || j>i) s = -NEG_;
        else {
            float acc=0;
            for (int d=0;d<DH_;d++) acc += qs[i*QLD_+d]*ks[j*QLD_+d];
            s = acc*temp + bias[(h*W_+i)*W_+j];
        }
        sc[e]=s;
    }
    __syncthreads();
    if (tid < W_){
        int i=tid;
        float mx=-INFINITY;
        for (int j=0;j<W_;j++) mx=fmaxf(mx, sc[i*W_+j]);
        float sum=0;
        for (int j=0;j<W_;j++){ float e_=expf(sc[i*W_+j]-mx); sc[i*W_+j]=e_; sum+=e_; }
        float inv=1.f/sum;
        for (int j=0;j<W_;j++) sc[i*W_+j]*=inv;
    }
    __syncthreads();
    // PV + fused osum partials (wave = i-group, lane = d)
    int wavei = tid >> 6, d = tid & 63;
    float psum = 0.f;
    for (int i = wavei; i < W_; i += 4){
        float s=0;
        for (int j=0;j<W_;j++) s += sc[i*W_+j]*vs[j*DH_+d];
        obuf[(size_t)(rbase+i)*DIM_ + h*DH_ + d] = (__bf16)s;
        if (vf[i]) psum += s;
    }
    osacc[wavei][d] = psum;
    __syncthreads();
    if (tid < 64)
        osum[(size_t)bw*DIM_ + h*DH_ + tid] =
            osacc[0][tid]+osacc[1][tid]+osacc[2][tid]+osacc[3][tid];
}

// ---------------------------------------------------------------- fused we-path
__global__ __launch_bounds__(384) void wefuse_k(
    const float* __restrict__ osum, const float* __restrict__ we_lin,
    const float* __restrict__ we_q, const float* __restrict__ k2,
    const float* __restrict__ v2, const unsigned char* __restrict__ mask,
    const float* __restrict__ len, float* __restrict__ o2)
{
    int bw = blockIdx.x;
    int b = bw / NW_, w = bw % NW_;
    int tid = threadIdx.x;
    __shared__ float osr[768], werr[384], wqr[384], pp[W_];
    osr[tid]     = osum[(size_t)bw*DIM_ + tid];
    osr[tid+384] = osum[(size_t)bw*DIM_ + tid + 384];
    __syncthreads();
    float invlen = 1.f / len[bw];
    float s = 0;
    for (int k=0;k<768;k++) s += osr[k]*we_lin[(size_t)k*P_ + tid];
    werr[tid] = fmaxf(s*invlen, 0.f);
    __syncthreads();
    s = 0;
    for (int k=0;k<384;k++) s += werr[k]*we_q[(size_t)k*P_ + tid];
    wqr[tid] = s;
    __syncthreads();
    if (tid < W_){
        int g = w*W_ + tid;
        bool val = (g < N_) && (mask[b*N_+g]==0);
        float sv = -NEG_;
        if (val){
            float acc=0;
            const float* kr = k2 + (size_t)(bw*W_+tid)*P_;
            for (int c=0;c<P_;c++) acc += wqr[c]*kr[c];
            sv = acc * 0.05103103630798287f; // 384^-0.5
        }
        pp[tid]=sv;
    }
    __syncthreads();
    if (tid==0){
        float mx=-INFINITY;
        for (int j=0;j<W_;j++) mx=fmaxf(mx,pp[j]);
        float sum=0;
        for (int j=0;j<W_;j++){ float e=expf(pp[j]-mx); pp[j]=e; sum+=e; }
        float inv=1.f/sum;
        for (int j=0;j<W_;j++) pp[j]*=inv;
    }
    __syncthreads();
    if (tid < V4_){
        float sv=0;
        for (int j=0;j<W_;j++) sv += pp[j]*v2[(size_t)(bw*W_+j)*V4_ + tid];
        o2[(size_t)bw*V4_ + tid] = sv;
    }
}

// ---------------------------------------------------------------- launch

extern "C" void kernel_launch(void* const* d_in, const int* in_sizes, int n_in,
                              void* d_out, int out_size, void* d_ws, size_t ws_size,
                              hipStream_t stream)
{
    const float* x       = (const float*)d_in[0];
    const unsigned char* mask = (const unsigned char*)d_in[1];
    const float* ln1_g   = (const float*)d_in[2];
    const float* ln1_b   = (const float*)d_in[3];
    const float* qkv_W   = (const float*)d_in[4];
    const float* temp    = (const float*)d_in[5];
    const float* we_lin_W= (const float*)d_in[6];
    const float* we_q_W  = (const float*)d_in[7];
    const float* we_k_W  = (const float*)d_in[8];
    const float* we_v_W  = (const float*)d_in[9];
    const float* we_bos  = (const float*)d_in[10];
    const float* we_scale= (const float*)d_in[11];
    const float* out_W   = (const float*)d_in[12];
    const float* ln2_g   = (const float*)d_in[13];
    const float* ln2_b   = (const float*)d_in[14];
    const float* glu_W   = (const float*)d_in[15];
    const float* glu_b   = (const float*)d_in[16];
    const float* ffo_W   = (const float*)d_in[17];
    const float* ffo_b   = (const float*)d_in[18];
    const float* pb_W1   = (const float*)d_in[19];
    const float* pb_b1   = (const float*)d_in[20];
    const float* pb_W2   = (const float*)d_in[21];
    const float* pb_b2   = (const float*)d_in[22];
    const float* pb_W3   = (const float*)d_in[23];
    const float* pb_b3   = (const float*)d_in[24];

    float* xc = (float*)d_out;            // running x

    // ---- workspace layout (256B-aligned chunks) ----
    char* p = (char*)d_ws;
    auto alloc = [&](size_t bytes)->char* {
        char* r = p; p += (bytes + 255) & ~(size_t)255; return r;
    };
    float* f_outk = (float*)alloc((size_t)69*12*4);
    float* f_bias = (float*)alloc((size_t)HEADS_*W_*W_*4);
    float* f_sinu = (float*)alloc((size_t)W_*P_*4);
    float* f_len  = (float*)alloc((size_t)NWB_*4);
    float* f_osum = (float*)alloc((size_t)NWB_*DIM_*4);
    float* f_o2   = (float*)alloc((size_t)NWB_*V4_*4);
    float* f_o2p  = (float*)alloc((size_t)NWB_*DIM_*4);
    // packed bf16 weights (all layers)
    __bf16* w_qkv = (__bf16*)alloc((size_t)DEPTH_*96*2304*8*2);
    __bf16* w_kvo = (__bf16*)alloc((size_t)DEPTH_*96*1408*8*2);   // k2|v2|outproj
    __bf16* w_glu = (__bf16*)alloc((size_t)DEPTH_*96*6144*8*2);
    __bf16* w_ffo = (__bf16*)alloc((size_t)DEPTH_*384*768*8*2);
    // activation arena (attention phase)
    char* arena = p;
    __bf16* f_hpad = (__bf16*)alloc((size_t)NTPA_*DIM_*2);
    __bf16* f_qkvb = (__bf16*)alloc((size_t)NTP_*3*DIM_*2);
    __bf16* f_obuf = (__bf16*)alloc((size_t)NTPA_*DIM_*2);
    float*  f_k2   = (float*)alloc((size_t)NTP_*P_*4);
    float*  f_v2   = (float*)alloc((size_t)NTP_*V4_*4);
    // FFN overlay (hpad/qkvb/obuf/k2/v2 dead during FFN)
    __bf16* f_h2 = (__bf16*)arena;
    __bf16* f_ag = (__bf16*)(arena + (((size_t)NTOK_*DIM_*2 + 255) & ~(size_t)255));
    (void)ws_size; (void)in_sizes; (void)n_in; (void)out_size;

    // ---- init + weight packing ----
    hipMemcpyAsync(xc, x, (size_t)NTOK_*DIM_*sizeof(float),
                   hipMemcpyDeviceToDevice, stream);
    posbias1_k<<<69,192,0,stream>>>(pb_W1,pb_b1,pb_W2,pb_b2,pb_W3,pb_b3,f_outk);
    posbias2_k<<<(HEADS_*W_*W_+255)/256,256,0,stream>>>(f_outk, f_bias);
    sinu_k<<<W_,192,0,stream>>>(f_sinu);
    len_k<<<1,256,0,stream>>>(mask, f_len);
    pack_k<<<dim3(9,96,DEPTH_),256,0,stream>>>(qkv_W, w_qkv, 2304, 2304, 2304,
        (size_t)768*2304, (size_t)96*2304*8, 1, 0);
    pack_k<<<dim3(2,96,DEPTH_),256,0,stream>>>(we_k_W, w_kvo, 384, 384, 1408,
        (size_t)768*384, (size_t)96*1408*8, 0, 0);
    pack_k<<<dim3(1,96,DEPTH_),256,0,stream>>>(we_v_W, w_kvo, 192, 192, 1408,
        (size_t)768*192, (size_t)96*1408*8, 0, 384);
    pack_k<<<dim3(4,96,DEPTH_),256,0,stream>>>(out_W, w_kvo, 768, 832, 1408,
        (size_t)960*768, (size_t)96*1408*8, 0, 576);
    pack_k<<<dim3(24,96,DEPTH_),256,0,stream>>>(glu_W, w_glu, 6144, 6144, 6144,
        (size_t)768*6144, (size_t)96*6144*8, 0, 0);
    pack_k<<<dim3(3,384,DEPTH_),256,0,stream>>>(ffo_W, w_ffo, 768, 768, 768,
        (size_t)3072*768, (size_t)384*768*8, 0, 0);

    for (int l=0;l<DEPTH_;l++){
        // LN1 (padded, bf16 out)
        ln_k<<<NTP_,256,0,stream>>>(xc, ln1_g+l*DIM_, ln1_b+l*DIM_, f_hpad,
            nullptr, 1);
        // qkv = h @ Wqkv -> bf16 (columns permuted to [s][h][d])
        mgemm_k<1,false,128><<<dim3(18,65),256,0,stream>>>(f_hpad,
            w_qkv + (size_t)l*96*2304*8, nullptr, f_qkvb, nullptr, nullptr,
            nullptr, nullptr, nullptr, NTP_, DIM_, 3*DIM_, 3*DIM_, 3*DIM_);
        // windowed attention (+fused osum)
        attn_k<<<B_*HEADS_*NW_,256,0,stream>>>(f_qkvb, mask, f_bias, temp+l,
            f_obuf, f_osum);
        // merged k2 | v2 | out-proj (xc += obuf @ out_W[:768]), BM=128
        mgemm_k<8,false,128><<<dim3(11,65),256,0,stream>>>(f_obuf,
            w_kvo + (size_t)l*96*1408*8, f_k2, nullptr, f_v2, xc,
            nullptr, f_sinu, we_scale+l, NTP_, DIM_, 1344, 1408, 0);
        // fused we-path: wer -> wq -> scores -> softmax -> o2
        wefuse_k<<<NWB_,384,0,stream>>>(f_osum, we_lin_W + (size_t)l*DIM_*P_,
            we_q_W + (size_t)l*P_*P_, f_k2, f_v2, mask, f_len, f_o2);
        // o2 projection (fp32, o2shift folded in) -> o2p
        gemm0_k<<<dim3(12,4),256,0,stream>>>(f_o2, we_bos + (size_t)l*V4_,
            out_W + (size_t)l*(DIM_+V4_)*DIM_ + (size_t)DIM_*DIM_,
            f_o2p, NWB_, V4_, DIM_, DIM_);

        // FFN: LN2 reads (xc + o2p)
        ln_k<<<NTOK_,256,0,stream>>>(xc, ln2_g+l*DIM_, ln2_b+l*DIM_, f_h2,
            f_o2p, 0);
        // GLU: BM=256 (32 MFMA/wave/barrier)
        mgemm_k<4,true,256><<<dim3(48,32),256,0,stream>>>(f_h2,
            w_glu + (size_t)l*96*6144*8, nullptr, f_ag, nullptr, nullptr,
            glu_b + (size_t)l*2*FF_, nullptr, nullptr,
            NTOK_, DIM_, FF_, 2*FF_, FF_);
        // FFO: xc += acc + bias + o2p, BM=128
        mgemm_k<3,false,128><<<dim3(6,64),256,0,stream>>>(f_ag,
            w_ffo + (size_t)l*384*768*8, xc, nullptr, nullptr, nullptr,
            ffo_b + (size_t)l*DIM_, f_o2p, nullptr,
            NTOK_, FF_, DIM_, DIM_, DIM_);
    }
}

// Round 10
// 2026.298 us; speedup vs baseline: 1.4352x; 1.4352x over previous
//
#include <hip/hip_runtime.h>
#include <hip/hip_bf16.h>
#include <cstddef>
#include <cstdint>

#define B_ 4
#define N_ 2048
#define DIM_ 768
#define HEADS_ 12
#define DH_ 64
#define DEPTH_ 4
#define W_ 35
#define P_ 384
#define V4_ 192
#define FF_ 3072
#define NW_ 59                 // windows per batch (pad 17)
#define NPB_ (NW_*W_)          // 2065 padded tokens per batch
#define NTOK_ (B_*N_)          // 8192
#define NWB_ (B_*NW_)          // 236 windows total
#define NTP_ (NWB_*W_)         // 8260 padded tokens total
#define NTPA_ 8448             // NTP rounded up for A tiles
#define NEG_ 3.402823466e+38f
#define QLD_ 65                // padded q/k LDS row stride (bank-conflict fix)

typedef __bf16 bf16x8 __attribute__((ext_vector_type(8)));
typedef float  f32x4  __attribute__((ext_vector_type(4)));

// async global->LDS, 16B per lane (global src per-lane, LDS dst = base+lane*16)
#define GLOAD16(g, l) __builtin_amdgcn_global_load_lds( \
    (const __attribute__((address_space(1))) uint32_t*)(g), \
    (__attribute__((address_space(3))) uint32_t*)(l), 16, 0, 0)

// ---------------------------------------------------------------- setup

__global__ __launch_bounds__(192) void posbias1_k(
    const float* __restrict__ W1, const float* __restrict__ b1,
    const float* __restrict__ W2, const float* __restrict__ b2,
    const float* __restrict__ W3, const float* __restrict__ b3,
    float* __restrict__ outk)
{
    __shared__ float h1[192];
    __shared__ float h2[192];
    int i = blockIdx.x;
    int tid = threadIdx.x;
    float pos = (float)(i - 34);
    h1[tid] = fmaxf(pos*W1[tid] + b1[tid], 0.f);
    __syncthreads();
    float s = b2[tid];
    for (int k=0;k<192;k++) s += h1[k]*W2[k*192+tid];
    h2[tid] = fmaxf(s, 0.f);
    __syncthreads();
    if (tid < 12){
        float o = b3[tid];
        for (int k=0;k<192;k++) o += h2[k]*W3[k*12+tid];
        outk[i*12+tid] = o;
    }
}

__global__ void posbias2_k(const float* __restrict__ outk, float* __restrict__ bias)
{
    int e = threadIdx.x + blockIdx.x*blockDim.x;
    if (e >= HEADS_*W_*W_) return;
    int h=e/(W_*W_); int rem=e%(W_*W_); int i=rem/W_; int j=rem%W_;
    bias[e] = outk[(i-j+W_-1)*12 + h];
}

__global__ void sinu_k(float* __restrict__ sinu)
{
    int i = blockIdx.x;      // 0..34
    int k = threadIdx.x;     // 0..191
    float inv = powf(10000.f, -(float)k/192.f);
    float s = (float)i * inv;
    sinu[i*P_ + k]       = sinf(s);
    sinu[i*P_ + 192 + k] = cosf(s);
}

__global__ void len_k(const unsigned char* __restrict__ mask, float* __restrict__ len)
{
    int bw = threadIdx.x + blockIdx.x*blockDim.x;
    if (bw >= NWB_) return;
    int b = bw / NW_, w = bw % NW_;
    int cnt = 0;
    for (int t=0;t<W_;t++){
        int g = w*W_ + t;
        if (g < N_ && mask[b*N_+g]==0) cnt++;
    }
    len[bw] = fmaxf((float)cnt, 1.f);
}

// bosp[l] = bos[l] @ out_W[l][768:960]  (precomputed once)
__global__ __launch_bounds__(256) void bosproj_k(
    const float* __restrict__ bos, const float* __restrict__ outW,
    float* __restrict__ bosp)
{
    int l = blockIdx.y;
    int c = blockIdx.x*256 + threadIdx.x;
    if (c >= DIM_) return;
    const float* W2 = outW + (size_t)l*(DIM_+V4_)*DIM_ + (size_t)DIM_*DIM_;
    const float* bl = bos + (size_t)l*V4_;
    float s = 0;
    for (int k=0;k<V4_;k++) s += bl[k]*W2[(size_t)k*DIM_ + c];
    bosp[(size_t)l*DIM_ + c] = s;
}

// weight pack: fp32 [K][N] -> bf16 [K/8][Nld][8]; dst col = ncol0+n, src col n
// (or qkv-permuted). n in [N,Ncov) zero-fills. grid.x covers Ncov.
__global__ __launch_bounds__(256) void pack_k(
    const float* __restrict__ W, __bf16* __restrict__ Bp,
    int N, int Ncov, int Nld, size_t lsW, size_t lsB, int qkvperm, int ncol0)
{
    int n = blockIdx.x*256 + threadIdx.x;
    int k8 = blockIdx.y, l = blockIdx.z;
    if (n >= Ncov) return;
    bf16x8 v;
    if (n < N){
        int sn = n;
        if (qkvperm){ int s = n/768, hd = n - s*768; sn = hd*3 + s; }
        const float* w = W + lsW*l + (size_t)k8*8*N + sn;
        #pragma unroll
        for (int e=0;e<8;e++) v[e] = (__bf16)w[(size_t)e*N];
    } else {
        #pragma unroll
        for (int e=0;e<8;e++) v[e] = (__bf16)0.f;
    }
    *(bf16x8*)(Bp + lsB*l + ((size_t)k8*Nld + ncol0 + n)*8) = v;
}

// ---------------------------------------------------------------- layernorm
// o2p != null (padded=0 only): normalize x + shifted-o2-proj broadcast:
// row n, window widx=n/W -> (widx==0 ? bosp : o2p[bw-1]).
__global__ __launch_bounds__(256) void ln_k(
    const float* __restrict__ x, const float* __restrict__ g,
    const float* __restrict__ b, __bf16* __restrict__ out,
    const float* __restrict__ o2p, const float* __restrict__ bosp, int padded)
{
    int r = blockIdx.x;
    int tid = threadIdx.x;
    int lane = tid & 63, wave = tid >> 6;
    int row = r; bool real = true;
    if (padded){
        int bb = r / NPB_, n = r % NPB_;
        if (n >= N_) real = false;
        row = bb*N_ + n;
    }
    float v0=0,v1=0,v2=0;
    if (real){
        const float* xr = x + (size_t)row*DIM_;
        v0 = xr[tid]; v1 = xr[tid+256]; v2 = xr[tid+512];
        if (o2p){
            int bb = row / N_, nn = row % N_;
            int widx = nn / W_;
            const float* op = widx ? o2p + (size_t)(bb*NW_ + widx - 1)*DIM_
                                   : bosp;
            v0 += op[tid]; v1 += op[tid+256]; v2 += op[tid+512];
        }
    }
    float s1 = v0+v1+v2;
    float s2 = v0*v0+v1*v1+v2*v2;
    #pragma unroll
    for (int off=32; off; off>>=1){
        s1 += __shfl_xor(s1, off);
        s2 += __shfl_xor(s2, off);
    }
    __shared__ float a1[4], a2[4];
    if (lane==0){ a1[wave]=s1; a2[wave]=s2; }
    __syncthreads();
    s1 = a1[0]+a1[1]+a1[2]+a1[3];
    s2 = a2[0]+a2[1]+a2[2]+a2[3];
    float m   = s1 * (1.f/768.f);
    float var = s2 * (1.f/768.f) - m*m;
    float inv = rsqrtf(var + 1e-5f);
    __bf16* o = out + (size_t)r*DIM_;
    if (!real){ o[tid]=(__bf16)0.f; o[tid+256]=(__bf16)0.f; o[tid+512]=(__bf16)0.f; return; }
    o[tid]     = (__bf16)((v0-m)*inv*g[tid]     + b[tid]);
    o[tid+256] = (__bf16)((v1-m)*inv*g[tid+256] + b[tid+256]);
    o[tid+512] = (__bf16)((v2-m)*inv*g[tid+512] + b[tid+512]);
}

// ---------------------------------------------------------------- MFMA GEMM
// Tri-buffered LDS, one raw s_barrier per K-step, counted vmcnt(NL)
// (2-deep prefetch stays in flight across barriers; drain only at last step).
// 256 threads, 4 waves 2Mx2N. BM in {64,128}. setprio(1) around MFMA cluster.
// EPI 1: Cb = acc (bf16)
// EPI 3: FFO: Cf += acc + bias[c] + shifted_o2p(row)[c]   (extra=o2p, scale_ptr=bosp)
// EPI 4: GLU (DUAL): Cb = (acc+bias[c]) * silu(acc2+bias[c+FF])
// EPI 8: merged: c<384 -> Cf(k2)=acc+sinu*scale ; c<576 -> Cf2(v2)=acc ;
//        else Cx[tok(row)*DIM + c-576] += acc (pad rows skipped)
template<int EPI, bool DUAL, int BM>
__global__ __launch_bounds__(256) void mgemm_k(
    const __bf16* __restrict__ A, const __bf16* __restrict__ Bp,
    float* __restrict__ Cf, __bf16* __restrict__ Cb, float* __restrict__ Cf2,
    float* __restrict__ Cx,
    const float* __restrict__ bias, const float* __restrict__ extra,
    const float* __restrict__ scale_ptr,
    int M, int K, int Nc, int Nld, int Cld)
{
    constexpr int BN = DUAL ? 64 : 128;     // B cols per buffer
    constexpr int RS = BM / 2;              // rows per wave
    constexpr int MF = RS / 16;             // M frags per wave
    constexpr int NF = (BN/2) / 16;         // N frags per wave
    constexpr int AS = BM * 32;             // A elems per buffer
    constexpr int BS = BN * 32;             // B elems per buffer
    constexpr int ALD = BM / 64;            // A gloads per thread
    constexpr int NL  = ALD + 2;            // gloads per thread per tile
    __shared__ alignas(16) __bf16 As[3*AS];
    __shared__ alignas(16) __bf16 Bs[3*BS];
    __shared__ alignas(16) __bf16 Gs[DUAL ? 3*BS : 16];
    const int tid = threadIdx.x;
    const int lane = tid & 63, wave = tid >> 6;
    const int wr = wave >> 1, wc = wave & 1;
    const int m0 = blockIdx.y*BM;
    const int n0 = blockIdx.x*BN;
    const int lk = lane >> 4, lr = lane & 15;
    f32x4 acc[MF][NF] = {};
    f32x4 acc2[DUAL?MF:1][NF] = {};

    // per-thread staging pointers; advance by constants per staged tile
    const __bf16* aP[ALD];
    int aO[ALD];
    #pragma unroll
    for (int q=0;q<ALD;q++){
        int i = tid + q*256;
        int r = i & (BM-1), k8 = i / BM;
        aP[q] = A + (size_t)(m0+r)*K + k8*8;
        aO[q] = i*8;
    }
    const __bf16* bP[2];
    int bO[2];
    if constexpr (!DUAL){
        #pragma unroll
        for (int q=0;q<2;q++){
            int i = tid + q*256;
            int n = i & 127, k8 = i >> 7;
            bP[q] = Bp + ((size_t)k8*Nld + n0 + n)*8;
            bO[q] = i*8;
        }
    } else {
        int n = tid & 63, k8 = tid >> 6;
        bP[0] = Bp + ((size_t)k8*Nld + n0 + n)*8;
        bP[1] = bP[0] + (size_t)FF_*8;
        bO[0] = tid*8;
        bO[1] = tid*8;
    }
    const size_t bStep = (size_t)Nld*32;

    auto stage = [&](int wb){
        #pragma unroll
        for (int q=0;q<ALD;q++)
            GLOAD16(aP[q], As + wb*AS + aO[q]);
        if constexpr (!DUAL){
            GLOAD16(bP[0], Bs + wb*BS + bO[0]);
            GLOAD16(bP[1], Bs + wb*BS + bO[1]);
        } else {
            GLOAD16(bP[0], Bs + wb*BS + bO[0]);
            GLOAD16(bP[1], Gs + wb*BS + bO[1]);
        }
        #pragma unroll
        for (int q=0;q<ALD;q++) aP[q] += 32;
        bP[0] += bStep; bP[1] += bStep;
    };

    const int nk = K >> 5;          // nk >= 24 for all call sites
    stage(0);
    stage(1);
    int rb = 0;
    for (int t = 0; t < nk; ++t){
        if (t == nk-1)              asm volatile("s_waitcnt vmcnt(0)" ::: "memory");
        else if constexpr (NL == 3) asm volatile("s_waitcnt vmcnt(3)" ::: "memory");
        else                        asm volatile("s_waitcnt vmcnt(4)" ::: "memory");
        __builtin_amdgcn_s_barrier();
        __builtin_amdgcn_sched_barrier(0);
        if (t + 2 < nk){
            int wb = rb + 2; if (wb >= 3) wb -= 3;
            stage(wb);
        }
        const __bf16* as = As + rb*AS + (size_t)(lk*BM + wr*RS + lr)*8;
        const __bf16* bs = Bs + rb*BS + (size_t)(lk*BN + wc*(BN/2) + lr)*8;
        bf16x8 af[MF], bfr[NF];
        #pragma unroll
        for (int m=0;m<MF;m++) af[m] = *(const bf16x8*)(as + m*128);
        #pragma unroll
        for (int n=0;n<NF;n++) bfr[n] = *(const bf16x8*)(bs + n*128);
        __builtin_amdgcn_s_setprio(1);
        #pragma unroll
        for (int m=0;m<MF;m++)
            #pragma unroll
            for (int n=0;n<NF;n++)
                acc[m][n] = __builtin_amdgcn_mfma_f32_16x16x32_bf16(af[m], bfr[n], acc[m][n], 0,0,0);
        if constexpr (DUAL){
            const __bf16* gs = Gs + rb*BS + (size_t)(lk*BN + wc*(BN/2) + lr)*8;
            bf16x8 gfr[NF];
            #pragma unroll
            for (int n=0;n<NF;n++) gfr[n] = *(const bf16x8*)(gs + n*128);
            #pragma unroll
            for (int m=0;m<MF;m++)
                #pragma unroll
                for (int n=0;n<NF;n++)
                    acc2[m][n] = __builtin_amdgcn_mfma_f32_16x16x32_bf16(af[m], gfr[n], acc2[m][n], 0,0,0);
        }
        __builtin_amdgcn_s_setprio(0);
        rb++; if (rb >= 3) rb = 0;
    }

    const int lq = lane >> 4;
    #pragma unroll
    for (int m=0;m<MF;m++){
        #pragma unroll
        for (int r=0;r<4;r++){
            int row = m0 + wr*RS + m*16 + lq*4 + r;
            if (row >= M) continue;
            #pragma unroll
            for (int n=0;n<NF;n++){
                int col = n0 + wc*(BN/2) + n*16 + lr;
                if (col >= Nc) continue;
                float v = acc[m][n][r];
                if (EPI==1){
                    Cb[(size_t)row*Cld + col] = (__bf16)v;
                } else if (EPI==3){
                    int bb = row / N_, nn = row % N_;
                    int widx = nn / W_;
                    const float* src = widx
                        ? extra + (size_t)(bb*NW_ + widx - 1)*DIM_
                        : scale_ptr;   // bosp
                    Cf[(size_t)row*Cld + col] += v + bias[col] + src[col];
                } else if (EPI==4){
                    float a_ = v + bias[col];
                    float g_ = acc2[m][n][r] + bias[col + FF_];
                    Cb[(size_t)row*Cld + col] = (__bf16)(a_ * (g_ / (1.f + expf(-g_))));
                } else if (EPI==8){
                    if (col < P_){
                        int tt = (row % NPB_) % W_;
                        Cf[(size_t)row*P_ + col] = v + extra[tt*P_ + col]*scale_ptr[0];
                    } else if (col < 576){
                        Cf2[(size_t)row*V4_ + (col - P_)] = v;
                    } else {
                        int bb = row / NPB_, nn = row % NPB_;
                        if (nn < N_)
                            Cx[(size_t)(bb*N_ + nn)*DIM_ + (col - 576)] += v;
                    }
                }
            }
        }
    }
}

// ---------------------------------------------------------------- windowed attention (+fused osum)
// qkv layout (permuted pack): row-major [token][ s*768 + h*64 + d ]
// q/k LDS rows padded to QLD_=65 floats: kills the 35-way bank conflict in
// the QK^T and l2norm loops (stride 64 = all lanes on bank d%32).
__global__ __launch_bounds__(256) void attn_k(
    const __bf16* __restrict__ qkv, const unsigned char* __restrict__ mask,
    const float* __restrict__ bias, const float* __restrict__ temp_p,
    __bf16* __restrict__ obuf, float* __restrict__ osum)
{
    int bid = blockIdx.x;
    int w = bid % NW_;
    int h = (bid / NW_) % HEADS_;
    int b = bid / (NW_*HEADS_);
    int tid = threadIdx.x;
    __shared__ float qs[W_*QLD_], ks[W_*QLD_], vs[W_*DH_];
    __shared__ float sc[W_*W_];
    __shared__ float osacc[4][64];
    __shared__ int vf[W_];
    int bw = b*NW_ + w;
    int rbase = bw*W_;
    for (int e=tid; e<W_*DH_; e+=256){
        int t=e>>6, d=e&63;
        size_t idx = (size_t)(rbase+t)*(3*DIM_) + h*DH_ + d;
        qs[t*QLD_+d]=(float)qkv[idx];
        ks[t*QLD_+d]=(float)qkv[idx+768];
        vs[e]=(float)qkv[idx+1536];
    }
    if (tid < W_){
        int g = w*W_ + tid;
        vf[tid] = (g < N_) && (mask[b*N_+g]==0);
    }
    __syncthreads();
    for (int e=tid; e<2*W_; e+=256){
        float* src = (e<W_)? qs : ks;
        int t = (e<W_)? e : e-W_;
        float s=0;
        for (int d=0;d<DH_;d++){ float v=src[t*QLD_+d]; s+=v*v; }
        float inv = 1.f / fmaxf(sqrtf(s), 1e-12f);
        for (int d=0;d<DH_;d++) src[t*QLD_+d] *= inv;
    }
    __syncthreads();
    float temp = temp_p[0];
    for (int e=tid; e<W_*W_; e+=256){
        int i=e/W_, j=e%W_;
        float s;
        if (!vf[i] || !vf[j] || j>i) s = -NEG_;
        else {
            float acc=0;
            for (int d=0;d<DH_;d++) acc += qs[i*QLD_+d]*ks[j*QLD_+d];
            s = acc*temp + bias[(h*W_+i)*W_+j];
        }
        sc[e]=s;
    }
    __syncthreads();
    if (tid < W_){
        int i=tid;
        float mx=-INFINITY;
        for (int j=0;j<W_;j++) mx=fmaxf(mx, sc[i*W_+j]);
        float sum=0;
        for (int j=0;j<W_;j++){ float e_=expf(sc[i*W_+j]-mx); sc[i*W_+j]=e_; sum+=e_; }
        float inv=1.f/sum;
        for (int j=0;j<W_;j++) sc[i*W_+j]*=inv;
    }
    __syncthreads();
    // PV + fused osum partials (wave = i-group, lane = d)
    int wavei = tid >> 6, d = tid & 63;
    float psum = 0.f;
    for (int i = wavei; i < W_; i += 4){
        float s=0;
        for (int j=0;j<W_;j++) s += sc[i*W_+j]*vs[j*DH_+d];
        obuf[(size_t)(rbase+i)*DIM_ + h*DH_ + d] = (__bf16)s;
        if (vf[i]) psum += s;
    }
    osacc[wavei][d] = psum;
    __syncthreads();
    if (tid < 64)
        osum[(size_t)bw*DIM_ + h*DH_ + tid] =
            osacc[0][tid]+osacc[1][tid]+osacc[2][tid]+osacc[3][tid];
}

// ---------------------------------------------------------------- fused we-path
// wer = relu(osum@we_lin/len); wq = wer@we_q; scores; softmax; o2 = p@v2;
// then o2p'[bw] = o2 @ out_W2 (own-window projection; shift happens at read).
__global__ __launch_bounds__(384) void wefuse_k(
    const float* __restrict__ osum, const float* __restrict__ we_lin,
    const float* __restrict__ we_q, const float* __restrict__ k2,
    const float* __restrict__ v2, const unsigned char* __restrict__ mask,
    const float* __restrict__ len, const float* __restrict__ W2,
    float* __restrict__ o2p)
{
    int bw = blockIdx.x;
    int b = bw / NW_, w = bw % NW_;
    int tid = threadIdx.x;
    __shared__ float osr[768], werr[384], wqr[384], pp[W_], o2s[V4_];
    osr[tid]     = osum[(size_t)bw*DIM_ + tid];
    osr[tid+384] = osum[(size_t)bw*DIM_ + tid + 384];
    __syncthreads();
    float invlen = 1.f / len[bw];
    float s = 0;
    for (int k=0;k<768;k++) s += osr[k]*we_lin[(size_t)k*P_ + tid];
    werr[tid] = fmaxf(s*invlen, 0.f);
    __syncthreads();
    s = 0;
    for (int k=0;k<384;k++) s += werr[k]*we_q[(size_t)k*P_ + tid];
    wqr[tid] = s;
    __syncthreads();
    if (tid < W_){
        int g = w*W_ + tid;
        bool val = (g < N_) && (mask[b*N_+g]==0);
        float sv = -NEG_;
        if (val){
            float acc=0;
            const float* kr = k2 + (size_t)(bw*W_+tid)*P_;
            for (int c=0;c<P_;c++) acc += wqr[c]*kr[c];
            sv = acc * 0.05103103630798287f; // 384^-0.5
        }
        pp[tid]=sv;
    }
    __syncthreads();
    if (tid==0){
        float mx=-INFINITY;
        for (int j=0;j<W_;j++) mx=fmaxf(mx,pp[j]);
        float sum=0;
        for (int j=0;j<W_;j++){ float e=expf(pp[j]-mx); pp[j]=e; sum+=e; }
        float inv=1.f/sum;
        for (int j=0;j<W_;j++) pp[j]*=inv;
    }
    __syncthreads();
    if (tid < V4_){
        float sv=0;
        for (int j=0;j<W_;j++) sv += pp[j]*v2[(size_t)(bw*W_+j)*V4_ + tid];
        o2s[tid] = sv;
    }
    __syncthreads();
    // project own-window o2 through out_W[768:960] (192x768)
    #pragma unroll
    for (int c = tid; c < DIM_; c += 384){
        float s2 = 0;
        for (int k=0;k<V4_;k++) s2 += o2s[k]*W2[(size_t)k*DIM_ + c];
        o2p[(size_t)bw*DIM_ + c] = s2;
    }
}

// ---------------------------------------------------------------- launch

extern "C" void kernel_launch(void* const* d_in, const int* in_sizes, int n_in,
                              void* d_out, int out_size, void* d_ws, size_t ws_size,
                              hipStream_t stream)
{
    const float* x       = (const float*)d_in[0];
    const unsigned char* mask = (const unsigned char*)d_in[1];
    const float* ln1_g   = (const float*)d_in[2];
    const float* ln1_b   = (const float*)d_in[3];
    const float* qkv_W   = (const float*)d_in[4];
    const float* temp    = (const float*)d_in[5];
    const float* we_lin_W= (const float*)d_in[6];
    const float* we_q_W  = (const float*)d_in[7];
    const float* we_k_W  = (const float*)d_in[8];
    const float* we_v_W  = (const float*)d_in[9];
    const float* we_bos  = (const float*)d_in[10];
    const float* we_scale= (const float*)d_in[11];
    const float* out_W   = (const float*)d_in[12];
    const float* ln2_g   = (const float*)d_in[13];
    const float* ln2_b   = (const float*)d_in[14];
    const float* glu_W   = (const float*)d_in[15];
    const float* glu_b   = (const float*)d_in[16];
    const float* ffo_W   = (const float*)d_in[17];
    const float* ffo_b   = (const float*)d_in[18];
    const float* pb_W1   = (const float*)d_in[19];
    const float* pb_b1   = (const float*)d_in[20];
    const float* pb_W2   = (const float*)d_in[21];
    const float* pb_b2   = (const float*)d_in[22];
    const float* pb_W3   = (const float*)d_in[23];
    const float* pb_b3   = (const float*)d_in[24];

    float* xc = (float*)d_out;            // running x

    // ---- workspace layout (256B-aligned chunks) ----
    char* p = (char*)d_ws;
    auto alloc = [&](size_t bytes)->char* {
        char* r = p; p += (bytes + 255) & ~(size_t)255; return r;
    };
    float* f_outk = (float*)alloc((size_t)69*12*4);
    float* f_bias = (float*)alloc((size_t)HEADS_*W_*W_*4);
    float* f_sinu = (float*)alloc((size_t)W_*P_*4);
    float* f_len  = (float*)alloc((size_t)NWB_*4);
    float* f_osum = (float*)alloc((size_t)NWB_*DIM_*4);
    float* f_o2p  = (float*)alloc((size_t)NWB_*DIM_*4);
    float* f_bosp = (float*)alloc((size_t)DEPTH_*DIM_*4);
    // packed bf16 weights (all layers)
    __bf16* w_qkv = (__bf16*)alloc((size_t)DEPTH_*96*2304*8*2);
    __bf16* w_kvo = (__bf16*)alloc((size_t)DEPTH_*96*1408*8*2);   // k2|v2|outproj
    __bf16* w_glu = (__bf16*)alloc((size_t)DEPTH_*96*6144*8*2);
    __bf16* w_ffo = (__bf16*)alloc((size_t)DEPTH_*384*768*8*2);
    // activation arena (attention phase)
    char* arena = p;
    __bf16* f_hpad = (__bf16*)alloc((size_t)NTPA_*DIM_*2);
    __bf16* f_qkvb = (__bf16*)alloc((size_t)NTP_*3*DIM_*2);
    __bf16* f_obuf = (__bf16*)alloc((size_t)NTPA_*DIM_*2);
    float*  f_k2   = (float*)alloc((size_t)NTP_*P_*4);
    float*  f_v2   = (float*)alloc((size_t)NTP_*V4_*4);
    // FFN overlay (hpad/qkvb/obuf/k2/v2 dead during FFN)
    __bf16* f_h2 = (__bf16*)arena;
    __bf16* f_ag = (__bf16*)(arena + (((size_t)NTOK_*DIM_*2 + 255) & ~(size_t)255));
    (void)ws_size; (void)in_sizes; (void)n_in; (void)out_size;

    // ---- init + weight packing ----
    hipMemcpyAsync(xc, x, (size_t)NTOK_*DIM_*sizeof(float),
                   hipMemcpyDeviceToDevice, stream);
    posbias1_k<<<69,192,0,stream>>>(pb_W1,pb_b1,pb_W2,pb_b2,pb_W3,pb_b3,f_outk);
    posbias2_k<<<(HEADS_*W_*W_+255)/256,256,0,stream>>>(f_outk, f_bias);
    sinu_k<<<W_,192,0,stream>>>(f_sinu);
    len_k<<<1,256,0,stream>>>(mask, f_len);
    bosproj_k<<<dim3(3,DEPTH_),256,0,stream>>>(we_bos, out_W, f_bosp);
    pack_k<<<dim3(9,96,DEPTH_),256,0,stream>>>(qkv_W, w_qkv, 2304, 2304, 2304,
        (size_t)768*2304, (size_t)96*2304*8, 1, 0);
    pack_k<<<dim3(2,96,DEPTH_),256,0,stream>>>(we_k_W, w_kvo, 384, 384, 1408,
        (size_t)768*384, (size_t)96*1408*8, 0, 0);
    pack_k<<<dim3(1,96,DEPTH_),256,0,stream>>>(we_v_W, w_kvo, 192, 192, 1408,
        (size_t)768*192, (size_t)96*1408*8, 0, 384);
    pack_k<<<dim3(4,96,DEPTH_),256,0,stream>>>(out_W, w_kvo, 768, 832, 1408,
        (size_t)960*768, (size_t)96*1408*8, 0, 576);
    pack_k<<<dim3(24,96,DEPTH_),256,0,stream>>>(glu_W, w_glu, 6144, 6144, 6144,
        (size_t)768*6144, (size_t)96*6144*8, 0, 0);
    pack_k<<<dim3(3,384,DEPTH_),256,0,stream>>>(ffo_W, w_ffo, 768, 768, 768,
        (size_t)3072*768, (size_t)384*768*8, 0, 0);

    for (int l=0;l<DEPTH_;l++){
        const float* bosp_l = f_bosp + (size_t)l*DIM_;
        // LN1 (padded, bf16 out)
        ln_k<<<NTP_,256,0,stream>>>(xc, ln1_g+l*DIM_, ln1_b+l*DIM_, f_hpad,
            nullptr, nullptr, 1);
        // qkv = h @ Wqkv -> bf16 (columns permuted to [s][h][d])
        mgemm_k<1,false,128><<<dim3(18,65),256,0,stream>>>(f_hpad,
            w_qkv + (size_t)l*96*2304*8, nullptr, f_qkvb, nullptr, nullptr,
            nullptr, nullptr, nullptr, NTP_, DIM_, 3*DIM_, 3*DIM_, 3*DIM_);
        // windowed attention (+fused osum)
        attn_k<<<B_*HEADS_*NW_,256,0,stream>>>(f_qkvb, mask, f_bias, temp+l,
            f_obuf, f_osum);
        // merged k2 | v2 | out-proj (xc += obuf @ out_W[:768]), BM=64
        mgemm_k<8,false,64><<<dim3(11,130),256,0,stream>>>(f_obuf,
            w_kvo + (size_t)l*96*1408*8, f_k2, nullptr, f_v2, xc,
            nullptr, f_sinu, we_scale+l, NTP_, DIM_, 1344, 1408, 0);
        // fused we-path: wer -> wq -> scores -> softmax -> o2 -> o2p'(own)
        wefuse_k<<<NWB_,384,0,stream>>>(f_osum, we_lin_W + (size_t)l*DIM_*P_,
            we_q_W + (size_t)l*P_*P_, f_k2, f_v2, mask, f_len,
            out_W + (size_t)l*(DIM_+V4_)*DIM_ + (size_t)DIM_*DIM_, f_o2p);

        // FFN: LN2 reads xc + shifted(o2p'/bosp)
        ln_k<<<NTOK_,256,0,stream>>>(xc, ln2_g+l*DIM_, ln2_b+l*DIM_, f_h2,
            f_o2p, bosp_l, 0);
        // GLU: BM=128 dual (R8 config)
        mgemm_k<4,true,128><<<dim3(48,64),256,0,stream>>>(f_h2,
            w_glu + (size_t)l*96*6144*8, nullptr, f_ag, nullptr, nullptr,
            glu_b + (size_t)l*2*FF_, nullptr, nullptr,
            NTOK_, DIM_, FF_, 2*FF_, FF_);
        // FFO: xc += acc + bias + shifted(o2p'/bosp), BM=64 (R8 config)
        mgemm_k<3,false,64><<<dim3(6,128),256,0,stream>>>(f_ag,
            w_ffo + (size_t)l*384*768*8, xc, nullptr, nullptr, nullptr,
            ffo_b + (size_t)l*DIM_, f_o2p, bosp_l,
            NTOK_, FF_, DIM_, DIM_, DIM_);
    }
}

// Round 11
// 1987.165 us; speedup vs baseline: 1.4634x; 1.0197x over previous
//
#include <hip/hip_runtime.h>
#include <hip/hip_bf16.h>
#include <cstddef>
#include <cstdint>

#define B_ 4
#define N_ 2048
#define DIM_ 768
#define HEADS_ 12
#define DH_ 64
#define DEPTH_ 4
#define W_ 35
#define P_ 384
#define V4_ 192
#define FF_ 3072
#define NW_ 59                 // windows per batch (pad 17)
#define NPB_ (NW_*W_)          // 2065 padded tokens per batch
#define NTOK_ (B_*N_)          // 8192
#define NWB_ (B_*NW_)          // 236 windows total
#define NTP_ (NWB_*W_)         // 8260 padded tokens total
#define NTPA_ 8448             // NTP rounded up for A tiles
#define NEG_ 3.402823466e+38f
#define QLD_ 65                // padded q/k LDS row stride (bank-conflict fix)

typedef __bf16 bf16x8 __attribute__((ext_vector_type(8)));
typedef float  f32x4  __attribute__((ext_vector_type(4)));

// async global->LDS, 16B per lane (global src per-lane, LDS dst = base+lane*16)
#define GLOAD16(g, l) __builtin_amdgcn_global_load_lds( \
    (const __attribute__((address_space(1))) uint32_t*)(g), \
    (__attribute__((address_space(3))) uint32_t*)(l), 16, 0, 0)

// ---------------------------------------------------------------- setup

__global__ __launch_bounds__(192) void posbias1_k(
    const float* __restrict__ W1, const float* __restrict__ b1,
    const float* __restrict__ W2, const float* __restrict__ b2,
    const float* __restrict__ W3, const float* __restrict__ b3,
    float* __restrict__ outk)
{
    __shared__ float h1[192];
    __shared__ float h2[192];
    int i = blockIdx.x;
    int tid = threadIdx.x;
    float pos = (float)(i - 34);
    h1[tid] = fmaxf(pos*W1[tid] + b1[tid], 0.f);
    __syncthreads();
    float s = b2[tid];
    for (int k=0;k<192;k++) s += h1[k]*W2[k*192+tid];
    h2[tid] = fmaxf(s, 0.f);
    __syncthreads();
    if (tid < 12){
        float o = b3[tid];
        for (int k=0;k<192;k++) o += h2[k]*W3[k*12+tid];
        outk[i*12+tid] = o;
    }
}

__global__ void posbias2_k(const float* __restrict__ outk, float* __restrict__ bias)
{
    int e = threadIdx.x + blockIdx.x*blockDim.x;
    if (e >= HEADS_*W_*W_) return;
    int h=e/(W_*W_); int rem=e%(W_*W_); int i=rem/W_; int j=rem%W_;
    bias[e] = outk[(i-j+W_-1)*12 + h];
}

__global__ void sinu_k(float* __restrict__ sinu)
{
    int i = blockIdx.x;      // 0..34
    int k = threadIdx.x;     // 0..191
    float inv = powf(10000.f, -(float)k/192.f);
    float s = (float)i * inv;
    sinu[i*P_ + k]       = sinf(s);
    sinu[i*P_ + 192 + k] = cosf(s);
}

__global__ void len_k(const unsigned char* __restrict__ mask, float* __restrict__ len)
{
    int bw = threadIdx.x + blockIdx.x*blockDim.x;
    if (bw >= NWB_) return;
    int b = bw / NW_, w = bw % NW_;
    int cnt = 0;
    for (int t=0;t<W_;t++){
        int g = w*W_ + t;
        if (g < N_ && mask[b*N_+g]==0) cnt++;
    }
    len[bw] = fmaxf((float)cnt, 1.f);
}

// bosp[l] = bos[l] @ out_W[l][768:960]  (precomputed once)
__global__ __launch_bounds__(256) void bosproj_k(
    const float* __restrict__ bos, const float* __restrict__ outW,
    float* __restrict__ bosp)
{
    int l = blockIdx.y;
    int c = blockIdx.x*256 + threadIdx.x;
    if (c >= DIM_) return;
    const float* W2 = outW + (size_t)l*(DIM_+V4_)*DIM_ + (size_t)DIM_*DIM_;
    const float* bl = bos + (size_t)l*V4_;
    float s = 0;
    for (int k=0;k<V4_;k++) s += bl[k]*W2[(size_t)k*DIM_ + c];
    bosp[(size_t)l*DIM_ + c] = s;
}

// weight pack: fp32 [K][N] -> bf16 [K/8][Nld][8]; dst col = ncol0+n.
// mode 0: src col n. mode 1 (qkv): src (n%768)*3 + n/768.
// mode 2 (glu-interleave for 8-phase dual): packed col n -> bx=n/256,
//   c=n%256, wcq=c/64, n2=(c%64)/16, lr=c%16; j=bx*128+wcq*32+(n2>>1)*16+lr;
//   src = (n2&1) ? FF_+j : j.
// n in [N,Ncov) zero-fills.
__global__ __launch_bounds__(256) void pack_k(
    const float* __restrict__ W, __bf16* __restrict__ Bp,
    int N, int Ncov, int Nld, size_t lsW, size_t lsB, int mode, int ncol0)
{
    int n = blockIdx.x*256 + threadIdx.x;
    int k8 = blockIdx.y, l = blockIdx.z;
    if (n >= Ncov) return;
    bf16x8 v;
    if (n < N){
        int sn = n;
        if (mode == 1){ int s = n/768, hd = n - s*768; sn = hd*3 + s; }
        else if (mode == 2){
            int bx = n >> 8, c = n & 255;
            int wcq = c >> 6, n2 = (c & 63) >> 4, lr2 = c & 15;
            int j = bx*128 + wcq*32 + ((n2>>1)<<4) + lr2;
            sn = (n2 & 1) ? FF_ + j : j;
        }
        const float* w = W + lsW*l + (size_t)k8*8*N + sn;
        #pragma unroll
        for (int e=0;e<8;e++) v[e] = (__bf16)w[(size_t)e*N];
    } else {
        #pragma unroll
        for (int e=0;e<8;e++) v[e] = (__bf16)0.f;
    }
    *(bf16x8*)(Bp + lsB*l + ((size_t)k8*Nld + ncol0 + n)*8) = v;
}

// ---------------------------------------------------------------- layernorm
__global__ __launch_bounds__(256) void ln_k(
    const float* __restrict__ x, const float* __restrict__ g,
    const float* __restrict__ b, __bf16* __restrict__ out,
    const float* __restrict__ o2p, const float* __restrict__ bosp, int padded)
{
    int r = blockIdx.x;
    int tid = threadIdx.x;
    int lane = tid & 63, wave = tid >> 6;
    int row = r; bool real = true;
    if (padded){
        int bb = r / NPB_, n = r % NPB_;
        if (n >= N_) real = false;
        row = bb*N_ + n;
    }
    float v0=0,v1=0,v2=0;
    if (real){
        const float* xr = x + (size_t)row*DIM_;
        v0 = xr[tid]; v1 = xr[tid+256]; v2 = xr[tid+512];
        if (o2p){
            int bb = row / N_, nn = row % N_;
            int widx = nn / W_;
            const float* op = widx ? o2p + (size_t)(bb*NW_ + widx - 1)*DIM_
                                   : bosp;
            v0 += op[tid]; v1 += op[tid+256]; v2 += op[tid+512];
        }
    }
    float s1 = v0+v1+v2;
    float s2 = v0*v0+v1*v1+v2*v2;
    #pragma unroll
    for (int off=32; off; off>>=1){
        s1 += __shfl_xor(s1, off);
        s2 += __shfl_xor(s2, off);
    }
    __shared__ float a1[4], a2[4];
    if (lane==0){ a1[wave]=s1; a2[wave]=s2; }
    __syncthreads();
    s1 = a1[0]+a1[1]+a1[2]+a1[3];
    s2 = a2[0]+a2[1]+a2[2]+a2[3];
    float m   = s1 * (1.f/768.f);
    float var = s2 * (1.f/768.f) - m*m;
    float inv = rsqrtf(var + 1e-5f);
    __bf16* o = out + (size_t)r*DIM_;
    if (!real){ o[tid]=(__bf16)0.f; o[tid+256]=(__bf16)0.f; o[tid+512]=(__bf16)0.f; return; }
    o[tid]     = (__bf16)((v0-m)*inv*g[tid]     + b[tid]);
    o[tid+256] = (__bf16)((v1-m)*inv*g[tid+256] + b[tid+256]);
    o[tid+512] = (__bf16)((v2-m)*inv*g[tid+512] + b[tid+512]);
}

// ---------------------------------------------------------------- MFMA GEMM (2-phase tri-buffer)
// EPI 1: Cb = acc (bf16)
// EPI 3: FFO: Cf += acc + bias[c] + shifted_o2p(row)[c]
// EPI 8: merged: c<384 -> Cf(k2)=acc+sinu*scale ; c<576 -> Cf2(v2)=acc ;
//        else Cx[tok(row)*DIM + c-576] += acc (pad rows skipped)
template<int EPI, bool DUAL, int BM>
__global__ __launch_bounds__(256) void mgemm_k(
    const __bf16* __restrict__ A, const __bf16* __restrict__ Bp,
    float* __restrict__ Cf, __bf16* __restrict__ Cb, float* __restrict__ Cf2,
    float* __restrict__ Cx,
    const float* __restrict__ bias, const float* __restrict__ extra,
    const float* __restrict__ scale_ptr,
    int M, int K, int Nc, int Nld, int Cld)
{
    constexpr int BN = DUAL ? 64 : 128;
    constexpr int RS = BM / 2;
    constexpr int MF = RS / 16;
    constexpr int NF = (BN/2) / 16;
    constexpr int AS = BM * 32;
    constexpr int BS = BN * 32;
    constexpr int ALD = BM / 64;
    constexpr int NL  = ALD + 2;
    __shared__ alignas(16) __bf16 As[3*AS];
    __shared__ alignas(16) __bf16 Bs[3*BS];
    __shared__ alignas(16) __bf16 Gs[DUAL ? 3*BS : 16];
    const int tid = threadIdx.x;
    const int lane = tid & 63, wave = tid >> 6;
    const int wr = wave >> 1, wc = wave & 1;
    const int m0 = blockIdx.y*BM;
    const int n0 = blockIdx.x*BN;
    const int lk = lane >> 4, lr = lane & 15;
    f32x4 acc[MF][NF] = {};
    f32x4 acc2[DUAL?MF:1][NF] = {};

    const __bf16* aP[ALD];
    int aO[ALD];
    #pragma unroll
    for (int q=0;q<ALD;q++){
        int i = tid + q*256;
        int r = i & (BM-1), k8 = i / BM;
        aP[q] = A + (size_t)(m0+r)*K + k8*8;
        aO[q] = i*8;
    }
    const __bf16* bP[2];
    int bO[2];
    if constexpr (!DUAL){
        #pragma unroll
        for (int q=0;q<2;q++){
            int i = tid + q*256;
            int n = i & 127, k8 = i >> 7;
            bP[q] = Bp + ((size_t)k8*Nld + n0 + n)*8;
            bO[q] = i*8;
        }
    } else {
        int n = tid & 63, k8 = tid >> 6;
        bP[0] = Bp + ((size_t)k8*Nld + n0 + n)*8;
        bP[1] = bP[0] + (size_t)FF_*8;
        bO[0] = tid*8;
        bO[1] = tid*8;
    }
    const size_t bStep = (size_t)Nld*32;

    auto stage = [&](int wb){
        #pragma unroll
        for (int q=0;q<ALD;q++)
            GLOAD16(aP[q], As + wb*AS + aO[q]);
        if constexpr (!DUAL){
            GLOAD16(bP[0], Bs + wb*BS + bO[0]);
            GLOAD16(bP[1], Bs + wb*BS + bO[1]);
        } else {
            GLOAD16(bP[0], Bs + wb*BS + bO[0]);
            GLOAD16(bP[1], Gs + wb*BS + bO[1]);
        }
        #pragma unroll
        for (int q=0;q<ALD;q++) aP[q] += 32;
        bP[0] += bStep; bP[1] += bStep;
    };

    const int nk = K >> 5;
    stage(0);
    stage(1);
    int rb = 0;
    for (int t = 0; t < nk; ++t){
        if (t == nk-1)              asm volatile("s_waitcnt vmcnt(0)" ::: "memory");
        else if constexpr (NL == 3) asm volatile("s_waitcnt vmcnt(3)" ::: "memory");
        else                        asm volatile("s_waitcnt vmcnt(4)" ::: "memory");
        __builtin_amdgcn_s_barrier();
        __builtin_amdgcn_sched_barrier(0);
        if (t + 2 < nk){
            int wb = rb + 2; if (wb >= 3) wb -= 3;
            stage(wb);
        }
        const __bf16* as = As + rb*AS + (size_t)(lk*BM + wr*RS + lr)*8;
        const __bf16* bs = Bs + rb*BS + (size_t)(lk*BN + wc*(BN/2) + lr)*8;
        bf16x8 af[MF], bfr[NF];
        #pragma unroll
        for (int m=0;m<MF;m++) af[m] = *(const bf16x8*)(as + m*128);
        #pragma unroll
        for (int n=0;n<NF;n++) bfr[n] = *(const bf16x8*)(bs + n*128);
        __builtin_amdgcn_s_setprio(1);
        #pragma unroll
        for (int m=0;m<MF;m++)
            #pragma unroll
            for (int n=0;n<NF;n++)
                acc[m][n] = __builtin_amdgcn_mfma_f32_16x16x32_bf16(af[m], bfr[n], acc[m][n], 0,0,0);
        if constexpr (DUAL){
            const __bf16* gs = Gs + rb*BS + (size_t)(lk*BN + wc*(BN/2) + lr)*8;
            bf16x8 gfr[NF];
            #pragma unroll
            for (int n=0;n<NF;n++) gfr[n] = *(const bf16x8*)(gs + n*128);
            #pragma unroll
            for (int m=0;m<MF;m++)
                #pragma unroll
                for (int n=0;n<NF;n++)
                    acc2[m][n] = __builtin_amdgcn_mfma_f32_16x16x32_bf16(af[m], gfr[n], acc2[m][n], 0,0,0);
        }
        __builtin_amdgcn_s_setprio(0);
        rb++; if (rb >= 3) rb = 0;
    }

    const int lq = lane >> 4;
    #pragma unroll
    for (int m=0;m<MF;m++){
        #pragma unroll
        for (int r=0;r<4;r++){
            int row = m0 + wr*RS + m*16 + lq*4 + r;
            if (row >= M) continue;
            #pragma unroll
            for (int n=0;n<NF;n++){
                int col = n0 + wc*(BN/2) + n*16 + lr;
                if (col >= Nc) continue;
                float v = acc[m][n][r];
                if (EPI==1){
                    Cb[(size_t)row*Cld + col] = (__bf16)v;
                } else if (EPI==3){
                    int bb = row / N_, nn = row % N_;
                    int widx = nn / W_;
                    const float* src = widx
                        ? extra + (size_t)(bb*NW_ + widx - 1)*DIM_
                        : scale_ptr;   // bosp
                    Cf[(size_t)row*Cld + col] += v + bias[col] + src[col];
                } else if (EPI==4){
                    float a_ = v + bias[col];
                    float g_ = acc2[m][n][r] + bias[col + FF_];
                    Cb[(size_t)row*Cld + col] = (__bf16)(a_ * (g_ / (1.f + expf(-g_))));
                } else if (EPI==8){
                    if (col < P_){
                        int tt = (row % NPB_) % W_;
                        Cf[(size_t)row*P_ + col] = v + extra[tt*P_ + col]*scale_ptr[0];
                    } else if (col < 576){
                        Cf2[(size_t)row*V4_ + (col - P_)] = v;
                    } else {
                        int bb = row / NPB_, nn = row % NPB_;
                        if (nn < N_)
                            Cx[(size_t)(bb*N_ + nn)*DIM_ + (col - 576)] += v;
                    }
                }
            }
        }
    }
}

// ---------------------------------------------------------------- GLU 8-phase (m201 template port)
// 256 rows x 256 packed cols (=128 out cols, a/g interleaved at 16-col frags).
// 512 thr / 8 waves 2Mx4N, wave 128x64 packed. BK=64, 2 K-tiles per 8-phase
// iter, 2 LDS dbuf (128KB). Phases 0-3 read buf0 (kt=2j) staging kt=2j+1 into
// buf1 (one 16KB half/phase); phases 4-7 read buf1 staging kt=2j+2 into buf0.
// vmcnt(0) only at phases 0/4 (outstanding loads had 1-4 phases to land).
__global__ __launch_bounds__(512) void glu8_k(
    const __bf16* __restrict__ A, const __bf16* __restrict__ Bp,
    __bf16* __restrict__ Cb, const float* __restrict__ bias)
{
    __shared__ alignas(16) __bf16 As[2][16384];   // [k8 0..7][row 0..255][8]
    __shared__ alignas(16) __bf16 Bs[2][16384];   // [k8 0..7][pcol 0..255][8]
    const int tid = threadIdx.x;
    const int lane = tid & 63, wave = tid >> 6;
    const int wr = wave >> 2, wc = wave & 3;      // 2M x 4N
    const int m0 = blockIdx.y << 8;
    const int n0p = blockIdx.x << 8;              // packed col base
    const int lk = lane >> 4, lr = lane & 15;
    f32x4 acc[8][4] = {};

    auto stageA = [&](int buf, int kt, int h){
        #pragma unroll
        for (int q=0;q<2;q++){
            int i = tid + q*512;
            int k8 = i >> 7, r = i & 127;
            GLOAD16(A + (size_t)(m0 + h*128 + r)*DIM_ + kt*64 + k8*8,
                    &As[buf][((size_t)k8*256 + h*128 + r)*8]);
        }
    };
    auto stageB = [&](int buf, int kt, int h){
        #pragma unroll
        for (int q=0;q<2;q++){
            int i = tid + q*512;
            int k8 = i >> 7, c = i & 127;
            GLOAD16(Bp + ((size_t)(kt*8 + k8)*6144 + n0p + h*128 + c)*8,
                    &Bs[buf][((size_t)k8*256 + h*128 + c)*8]);
        }
    };
    auto stageHalf = [&](int buf, int kt, int h){
        if (h < 2) stageA(buf, kt, h); else stageB(buf, kt, h-2);
    };

    // prologue: kt0 -> buf0, kt1 -> buf1
    #pragma unroll
    for (int h=0;h<4;h++) stageHalf(0, 0, h);
    #pragma unroll
    for (int h=0;h<4;h++) stageHalf(1, 1, h);
    asm volatile("s_waitcnt vmcnt(8)" ::: "memory");   // buf0 landed
    __builtin_amdgcn_s_barrier();
    __builtin_amdgcn_sched_barrier(0);

    const int niter = (DIM_/64) / 2;   // 6
    for (int j = 0; j < niter; ++j){
        #pragma unroll
        for (int p = 0; p < 8; ++p){
            const int g = p >> 2;          // buffer read this phase
            const int q = p & 3;
            if (p == 0){
                if (j > 0) asm volatile("s_waitcnt vmcnt(0)" ::: "memory");
            } else if (p == 4){
                asm volatile("s_waitcnt vmcnt(0)" ::: "memory");
            }
            // stage one half-tile (2 gloads/thread)
            if (g == 0){
                if (j >= 1) stageHalf(1, 2*j+1, q);
            } else {
                if (2*j+2 < DIM_/64) stageHalf(0, 2*j+2, q);
            }
            // ds-read this phase's quadrant (12 x b128)
            const int rbase = wr*128 + (q&1)*64;
            const int cbase = wc*64  + ((q>>1))*32;
            const __bf16* as = &As[g][0];
            const __bf16* bs = &Bs[g][0];
            bf16x8 af[2][4], bfr[2][2];
            #pragma unroll
            for (int s=0;s<2;s++){
                #pragma unroll
                for (int m=0;m<4;m++)
                    af[s][m] = *(const bf16x8*)(as + ((size_t)((s*4+lk)*256 + rbase + m*16 + lr))*8);
                #pragma unroll
                for (int n=0;n<2;n++)
                    bfr[s][n] = *(const bf16x8*)(bs + ((size_t)((s*4+lk)*256 + cbase + n*16 + lr))*8);
            }
            __builtin_amdgcn_s_barrier();
            __builtin_amdgcn_sched_barrier(0);
            __builtin_amdgcn_s_setprio(1);
            #pragma unroll
            for (int s=0;s<2;s++)
                #pragma unroll
                for (int m=0;m<4;m++)
                    #pragma unroll
                    for (int n=0;n<2;n++)
                        acc[(q&1)*4 + m][(q>>1)*2 + n] =
                            __builtin_amdgcn_mfma_f32_16x16x32_bf16(
                                af[s][m], bfr[s][n],
                                acc[(q&1)*4 + m][(q>>1)*2 + n], 0,0,0);
            __builtin_amdgcn_s_setprio(0);
            __builtin_amdgcn_s_barrier();
            __builtin_amdgcn_sched_barrier(0);
        }
    }

    // epilogue: a = acc[mm][hh*2], g = acc[mm][hh*2+1]; silu-combine
    const int lq = lane >> 4;
    const int jc0 = (blockIdx.x << 7) + wc*32 + lr;
    #pragma unroll
    for (int mm=0;mm<8;mm++){
        int rowb = m0 + wr*128 + mm*16 + lq*4;
        #pragma unroll
        for (int hh=0; hh<2; hh++){
            int col = jc0 + hh*16;
            float ba = bias[col], bg = bias[col + FF_];
            #pragma unroll
            for (int r=0;r<4;r++){
                float a_ = acc[mm][hh*2][r] + ba;
                float g_ = acc[mm][hh*2+1][r] + bg;
                Cb[(size_t)(rowb + r)*FF_ + col] =
                    (__bf16)(a_ * (g_/(1.f + expf(-g_))));
            }
        }
    }
}

// ---------------------------------------------------------------- windowed attention (+fused osum)
__global__ __launch_bounds__(256) void attn_k(
    const __bf16* __restrict__ qkv, const unsigned char* __restrict__ mask,
    const float* __restrict__ bias, const float* __restrict__ temp_p,
    __bf16* __restrict__ obuf, float* __restrict__ osum)
{
    int bid = blockIdx.x;
    int w = bid % NW_;
    int h = (bid / NW_) % HEADS_;
    int b = bid / (NW_*HEADS_);
    int tid = threadIdx.x;
    __shared__ float qs[W_*QLD_], ks[W_*QLD_], vs[W_*DH_];
    __shared__ float sc[W_*W_];
    __shared__ float osacc[4][64];
    __shared__ int vf[W_];
    int bw = b*NW_ + w;
    int rbase = bw*W_;
    for (int e=tid; e<W_*DH_; e+=256){
        int t=e>>6, d=e&63;
        size_t idx = (size_t)(rbase+t)*(3*DIM_) + h*DH_ + d;
        qs[t*QLD_+d]=(float)qkv[idx];
        ks[t*QLD_+d]=(float)qkv[idx+768];
        vs[e]=(float)qkv[idx+1536];
    }
    if (tid < W_){
        int g = w*W_ + tid;
        vf[tid] = (g < N_) && (mask[b*N_+g]==0);
    }
    __syncthreads();
    for (int e=tid; e<2*W_; e+=256){
        float* src = (e<W_)? qs : ks;
        int t = (e<W_)? e : e-W_;
        float s=0;
        for (int d=0;d<DH_;d++){ float v=src[t*QLD_+d]; s+=v*v; }
        float inv = 1.f / fmaxf(sqrtf(s), 1e-12f);
        for (int d=0;d<DH_;d++) src[t*QLD_+d] *= inv;
    }
    __syncthreads();
    float temp = temp_p[0];
    for (int e=tid; e<W_*W_; e+=256){
        int i=e/W_, j=e%W_;
        float s;
        if (!vf[i] || !vf[j] || j>i) s = -NEG_;
        else {
            float acc=0;
            for (int d=0;d<DH_;d++) acc += qs[i*QLD_+d]*ks[j*QLD_+d];
            s = acc*temp + bias[(h*W_+i)*W_+j];
        }
        sc[e]=s;
    }
    __syncthreads();
    if (tid < W_){
        int i=tid;
        float mx=-INFINITY;
        for (int j=0;j<W_;j++) mx=fmaxf(mx, sc[i*W_+j]);
        float sum=0;
        for (int j=0;j<W_;j++){ float e_=expf(sc[i*W_+j]-mx); sc[i*W_+j]=e_; sum+=e_; }
        float inv=1.f/sum;
        for (int j=0;j<W_;j++) sc[i*W_+j]*=inv;
    }
    __syncthreads();
    int wavei = tid >> 6, d = tid & 63;
    float psum = 0.f;
    for (int i = wavei; i < W_; i += 4){
        float s=0;
        for (int j=0;j<W_;j++) s += sc[i*W_+j]*vs[j*DH_+d];
        obuf[(size_t)(rbase+i)*DIM_ + h*DH_ + d] = (__bf16)s;
        if (vf[i]) psum += s;
    }
    osacc[wavei][d] = psum;
    __syncthreads();
    if (tid < 64)
        osum[(size_t)bw*DIM_ + h*DH_ + tid] =
            osacc[0][tid]+osacc[1][tid]+osacc[2][tid]+osacc[3][tid];
}

// ---------------------------------------------------------------- fused we-path
__global__ __launch_bounds__(384) void wefuse_k(
    const float* __restrict__ osum, const float* __restrict__ we_lin,
    const float* __restrict__ we_q, const float* __restrict__ k2,
    const float* __restrict__ v2, const unsigned char* __restrict__ mask,
    const float* __restrict__ len, const float* __restrict__ W2,
    float* __restrict__ o2p)
{
    int bw = blockIdx.x;
    int b = bw / NW_, w = bw % NW_;
    int tid = threadIdx.x;
    __shared__ float osr[768], werr[384], wqr[384], pp[W_], o2s[V4_];
    osr[tid]     = osum[(size_t)bw*DIM_ + tid];
    osr[tid+384] = osum[(size_t)bw*DIM_ + tid + 384];
    __syncthreads();
    float invlen = 1.f / len[bw];
    float s = 0;
    for (int k=0;k<768;k++) s += osr[k]*we_lin[(size_t)k*P_ + tid];
    werr[tid] = fmaxf(s*invlen, 0.f);
    __syncthreads();
    s = 0;
    for (int k=0;k<384;k++) s += werr[k]*we_q[(size_t)k*P_ + tid];
    wqr[tid] = s;
    __syncthreads();
    if (tid < W_){
        int g = w*W_ + tid;
        bool val = (g < N_) && (mask[b*N_+g]==0);
        float sv = -NEG_;
        if (val){
            float acc=0;
            const float* kr = k2 + (size_t)(bw*W_+tid)*P_;
            for (int c=0;c<P_;c++) acc += wqr[c]*kr[c];
            sv = acc * 0.05103103630798287f; // 384^-0.5
        }
        pp[tid]=sv;
    }
    __syncthreads();
    if (tid==0){
        float mx=-INFINITY;
        for (int j=0;j<W_;j++) mx=fmaxf(mx,pp[j]);
        float sum=0;
        for (int j=0;j<W_;j++){ float e=expf(pp[j]-mx); pp[j]=e; sum+=e; }
        float inv=1.f/sum;
        for (int j=0;j<W_;j++) pp[j]*=inv;
    }
    __syncthreads();
    if (tid < V4_){
        float sv=0;
        for (int j=0;j<W_;j++) sv += pp[j]*v2[(size_t)(bw*W_+j)*V4_ + tid];
        o2s[tid] = sv;
    }
    __syncthreads();
    #pragma unroll
    for (int c = tid; c < DIM_; c += 384){
        float s2 = 0;
        for (int k=0;k<V4_;k++) s2 += o2s[k]*W2[(size_t)k*DIM_ + c];
        o2p[(size_t)bw*DIM_ + c] = s2;
    }
}

// ---------------------------------------------------------------- launch

extern "C" void kernel_launch(void* const* d_in, const int* in_sizes, int n_in,
                              void* d_out, int out_size, void* d_ws, size_t ws_size,
                              hipStream_t stream)
{
    const float* x       = (const float*)d_in[0];
    const unsigned char* mask = (const unsigned char*)d_in[1];
    const float* ln1_g   = (const float*)d_in[2];
    const float* ln1_b   = (const float*)d_in[3];
    const float* qkv_W   = (const float*)d_in[4];
    const float* temp    = (const float*)d_in[5];
    const float* we_lin_W= (const float*)d_in[6];
    const float* we_q_W  = (const float*)d_in[7];
    const float* we_k_W  = (const float*)d_in[8];
    const float* we_v_W  = (const float*)d_in[9];
    const float* we_bos  = (const float*)d_in[10];
    const float* we_scale= (const float*)d_in[11];
    const float* out_W   = (const float*)d_in[12];
    const float* ln2_g   = (const float*)d_in[13];
    const float* ln2_b   = (const float*)d_in[14];
    const float* glu_W   = (const float*)d_in[15];
    const float* glu_b   = (const float*)d_in[16];
    const float* ffo_W   = (const float*)d_in[17];
    const float* ffo_b   = (const float*)d_in[18];
    const float* pb_W1   = (const float*)d_in[19];
    const float* pb_b1   = (const float*)d_in[20];
    const float* pb_W2   = (const float*)d_in[21];
    const float* pb_b2   = (const float*)d_in[22];
    const float* pb_W3   = (const float*)d_in[23];
    const float* pb_b3   = (const float*)d_in[24];

    float* xc = (float*)d_out;            // running x

    // ---- workspace layout (256B-aligned chunks) ----
    char* p = (char*)d_ws;
    auto alloc = [&](size_t bytes)->char* {
        char* r = p; p += (bytes + 255) & ~(size_t)255; return r;
    };
    float* f_outk = (float*)alloc((size_t)69*12*4);
    float* f_bias = (float*)alloc((size_t)HEADS_*W_*W_*4);
    float* f_sinu = (float*)alloc((size_t)W_*P_*4);
    float* f_len  = (float*)alloc((size_t)NWB_*4);
    float* f_osum = (float*)alloc((size_t)NWB_*DIM_*4);
    float* f_o2p  = (float*)alloc((size_t)NWB_*DIM_*4);
    float* f_bosp = (float*)alloc((size_t)DEPTH_*DIM_*4);
    // packed bf16 weights (all layers)
    __bf16* w_qkv = (__bf16*)alloc((size_t)DEPTH_*96*2304*8*2);
    __bf16* w_kvo = (__bf16*)alloc((size_t)DEPTH_*96*1408*8*2);   // k2|v2|outproj
    __bf16* w_glu = (__bf16*)alloc((size_t)DEPTH_*96*6144*8*2);   // interleaved a|g
    __bf16* w_ffo = (__bf16*)alloc((size_t)DEPTH_*384*768*8*2);
    // activation arena (attention phase)
    char* arena = p;
    __bf16* f_hpad = (__bf16*)alloc((size_t)NTPA_*DIM_*2);
    __bf16* f_qkvb = (__bf16*)alloc((size_t)NTP_*3*DIM_*2);
    __bf16* f_obuf = (__bf16*)alloc((size_t)NTPA_*DIM_*2);
    float*  f_k2   = (float*)alloc((size_t)NTP_*P_*4);
    float*  f_v2   = (float*)alloc((size_t)NTP_*V4_*4);
    // FFN overlay (hpad/qkvb/obuf/k2/v2 dead during FFN)
    __bf16* f_h2 = (__bf16*)arena;
    __bf16* f_ag = (__bf16*)(arena + (((size_t)NTOK_*DIM_*2 + 255) & ~(size_t)255));
    (void)ws_size; (void)in_sizes; (void)n_in; (void)out_size;

    // ---- init + weight packing ----
    hipMemcpyAsync(xc, x, (size_t)NTOK_*DIM_*sizeof(float),
                   hipMemcpyDeviceToDevice, stream);
    posbias1_k<<<69,192,0,stream>>>(pb_W1,pb_b1,pb_W2,pb_b2,pb_W3,pb_b3,f_outk);
    posbias2_k<<<(HEADS_*W_*W_+255)/256,256,0,stream>>>(f_outk, f_bias);
    sinu_k<<<W_,192,0,stream>>>(f_sinu);
    len_k<<<1,256,0,stream>>>(mask, f_len);
    bosproj_k<<<dim3(3,DEPTH_),256,0,stream>>>(we_bos, out_W, f_bosp);
    pack_k<<<dim3(9,96,DEPTH_),256,0,stream>>>(qkv_W, w_qkv, 2304, 2304, 2304,
        (size_t)768*2304, (size_t)96*2304*8, 1, 0);
    pack_k<<<dim3(2,96,DEPTH_),256,0,stream>>>(we_k_W, w_kvo, 384, 384, 1408,
        (size_t)768*384, (size_t)96*1408*8, 0, 0);
    pack_k<<<dim3(1,96,DEPTH_),256,0,stream>>>(we_v_W, w_kvo, 192, 192, 1408,
        (size_t)768*192, (size_t)96*1408*8, 0, 384);
    pack_k<<<dim3(4,96,DEPTH_),256,0,stream>>>(out_W, w_kvo, 768, 832, 1408,
        (size_t)960*768, (size_t)96*1408*8, 0, 576);
    pack_k<<<dim3(24,96,DEPTH_),256,0,stream>>>(glu_W, w_glu, 6144, 6144, 6144,
        (size_t)768*6144, (size_t)96*6144*8, 2, 0);
    pack_k<<<dim3(3,384,DEPTH_),256,0,stream>>>(ffo_W, w_ffo, 768, 768, 768,
        (size_t)3072*768, (size_t)384*768*8, 0, 0);

    for (int l=0;l<DEPTH_;l++){
        const float* bosp_l = f_bosp + (size_t)l*DIM_;
        // LN1 (padded, bf16 out)
        ln_k<<<NTP_,256,0,stream>>>(xc, ln1_g+l*DIM_, ln1_b+l*DIM_, f_hpad,
            nullptr, nullptr, 1);
        // qkv = h @ Wqkv -> bf16 (columns permuted to [s][h][d])
        mgemm_k<1,false,128><<<dim3(18,65),256,0,stream>>>(f_hpad,
            w_qkv + (size_t)l*96*2304*8, nullptr, f_qkvb, nullptr, nullptr,
            nullptr, nullptr, nullptr, NTP_, DIM_, 3*DIM_, 3*DIM_, 3*DIM_);
        // windowed attention (+fused osum)
        attn_k<<<B_*HEADS_*NW_,256,0,stream>>>(f_qkvb, mask, f_bias, temp+l,
            f_obuf, f_osum);
        // merged k2 | v2 | out-proj (xc += obuf @ out_W[:768]), BM=64
        mgemm_k<8,false,64><<<dim3(11,130),256,0,stream>>>(f_obuf,
            w_kvo + (size_t)l*96*1408*8, f_k2, nullptr, f_v2, xc,
            nullptr, f_sinu, we_scale+l, NTP_, DIM_, 1344, 1408, 0);
        // fused we-path: wer -> wq -> scores -> softmax -> o2 -> o2p'(own)
        wefuse_k<<<NWB_,384,0,stream>>>(f_osum, we_lin_W + (size_t)l*DIM_*P_,
            we_q_W + (size_t)l*P_*P_, f_k2, f_v2, mask, f_len,
            out_W + (size_t)l*(DIM_+V4_)*DIM_ + (size_t)DIM_*DIM_, f_o2p);

        // FFN: LN2 reads xc + shifted(o2p'/bosp)
        ln_k<<<NTOK_,256,0,stream>>>(xc, ln2_g+l*DIM_, ln2_b+l*DIM_, f_h2,
            f_o2p, bosp_l, 0);
        // GLU: 8-phase 256x256 template (a/g interleaved dual, fused silu)
        glu8_k<<<dim3(24,32),512,0,stream>>>(f_h2,
            w_glu + (size_t)l*96*6144*8, f_ag, glu_b + (size_t)l*2*FF_);
        // FFO: xc += acc + bias + shifted(o2p'/bosp), BM=64
        mgemm_k<3,false,64><<<dim3(6,128),256,0,stream>>>(f_ag,
            w_ffo + (size_t)l*384*768*8, xc, nullptr, nullptr, nullptr,
            ffo_b + (size_t)l*DIM_, f_o2p, bosp_l,
            NTOK_, FF_, DIM_, DIM_, DIM_);
    }
}